// Round 2
// 749.851 us; speedup vs baseline: 1.0201x; 1.0201x over previous
//
#include <hip/hip_runtime.h>
#include <hip/hip_bf16.h>

// Experts MLP: B=4,E=8,S=1024,D=1024,H=2048. fp32 in/out, bf16 MFMA compute.
// Round 3 (resubmit after infra failure): GEMM K-loop restructured from m97
// single-buffer (stage -> vmcnt(0) drain -> compute) to the T3-minimum
// 2-phase double-buffered prefetch:
//   prologue: STAGE(buf0, kt=0); syncthreads;
//   loop kt:  STAGE(buf[kt+1 & 1], kt+1);  // async, flies during compute
//             ds_read buf[kt&1]; setprio(1); 16 MFMA; setprio(0);
//             __syncthreads();             // vmcnt(0)+lgkm drain+barrier
// Race-free: buf[x] is staged only after all waves' ds_reads of buf[x]
// completed (lgkmcnt(0) inside the prior iteration's syncthreads precedes
// the barrier all waves cross before the stage issue).

typedef __attribute__((ext_vector_type(8))) short bf16x8;
typedef __attribute__((ext_vector_type(4))) float f32x4;

__device__ __forceinline__ ushort f2bf(float f) {
    __hip_bfloat16 h = __float2bfloat16(f);
    return *(ushort*)&h;
}

__device__ __forceinline__ void async16(const ushort* g, ushort* l) {
    __builtin_amdgcn_global_load_lds(
        (const __attribute__((address_space(1))) unsigned int*)g,
        (__attribute__((address_space(3))) unsigned int*)l, 16, 0, 0);
}

// ---------------------------------------------------------------------------
// fp32 -> bf16 elementwise cast, float4 -> 4x bf16 per thread-iter.
// ---------------------------------------------------------------------------
__global__ __launch_bounds__(256) void cvt_f32_bf16(
    const float4* __restrict__ src, uint2* __restrict__ dst, long n4)
{
    long i = (long)blockIdx.x * 256 + threadIdx.x;
    const long stride = (long)gridDim.x * 256;
    for (; i < n4; i += stride) {
        float4 v = src[i];
        uint2 o;
        o.x = (unsigned)f2bf(v.x) | ((unsigned)f2bf(v.y) << 16);
        o.y = (unsigned)f2bf(v.z) | ((unsigned)f2bf(v.w) << 16);
        dst[i] = o;
    }
}

// ---------------------------------------------------------------------------
// Transpose+convert: fp32 (R,C) -> bf16 (C,R), per expert (grid.z).
// grid(C/64, R/64, E), 256 threads, 64x64 tile via LDS (65-pad).
// ---------------------------------------------------------------------------
__global__ __launch_bounds__(256) void transpose_cvt(
    const float* __restrict__ src, ushort* __restrict__ dst, int R, int C)
{
    __shared__ float tile[64][65];
    const int e = blockIdx.z;
    const float* s = src + (size_t)e * R * C;
    ushort* d = dst + (size_t)e * R * C;
    const int r0 = blockIdx.y * 64, c0 = blockIdx.x * 64;
    const int tid = threadIdx.x;

    const int tr = tid >> 4;          // 0..15
    const int tc = (tid & 15) * 4;    // 0..60
#pragma unroll
    for (int j = 0; j < 4; ++j) {
        const int row = tr + j * 16;
        float4 v = *(const float4*)&s[(size_t)(r0 + row) * C + c0 + tc];
        tile[row][tc] = v.x; tile[row][tc + 1] = v.y;
        tile[row][tc + 2] = v.z; tile[row][tc + 3] = v.w;
    }
    __syncthreads();

    const int cc = tid >> 2;          // dst row (src col) 0..63
    const int rq = (tid & 3) * 16;    // dst col base
    ushort o[16];
#pragma unroll
    for (int j = 0; j < 16; ++j) o[j] = f2bf(tile[rq + j][cc]);
    *(uint4*)&d[(size_t)(c0 + cc) * R + r0 + rq]     = *(uint4*)&o[0];
    *(uint4*)&d[(size_t)(c0 + cc) * R + r0 + rq + 8] = *(uint4*)&o[8];
}

// ---------------------------------------------------------------------------
// GEMM: C(M,N) = A(M,K) @ BT(N,K)^T + bias(fp32), optional exact GELU.
// A,BT bf16; fp32 accum; OUT fp32 (OUTF32=1) or bf16.
// 128x128 tile, 4 waves 2x2, 4x4 of 16x16x32 MFMA, BK=32, width-16
// global_load_lds staging, DOUBLE-BUFFERED with next-tile prefetch.
// grid(N/128, M/128, nE).
// ---------------------------------------------------------------------------
template <int GELU, int OUTF32>
__global__ __launch_bounds__(256) void gemm_bt(
    const ushort* __restrict__ A,
    const ushort* __restrict__ BT,
    const float* __restrict__ bias,
    void* __restrict__ Cv,
    int M, int N, int K)
{
    const int e = blockIdx.z;
    const ushort* Ab = A + (size_t)e * M * K;
    const ushort* Bb = BT + (size_t)e * N * K;
    const float* biasb = bias + (size_t)e * N;

    const int row0 = blockIdx.y * 128;
    const int col0 = blockIdx.x * 128;
    const int tid = threadIdx.x;
    const int lane = tid & 63;
    const int wave = tid >> 6;
    const int wy = wave >> 1, wx = wave & 1;
    const int lr = lane & 15;   // row (A) / col (B) within 16
    const int lk = lane >> 4;   // k-quad 0..3

    // double buffers: buf b at element offset b*4096 (128 rows x 32 cols)
    __shared__ ushort sA[2 * 128 * 32];
    __shared__ ushort sB[2 * 128 * 32];

    f32x4 acc[4][4] = {};

    // Per-thread staging addresses (loop-invariant; advance by kt*32 elems).
    // Chunk c (16B): row = c>>2, kc = c&3; this thread owns chunks tid, tid+256.
    const int ca = tid;
    const int cb = 256 + tid;
    const ushort* gA0 = Ab + (size_t)(row0 + (ca >> 2)) * K + (ca & 3) * 8;
    const ushort* gA1 = Ab + (size_t)(row0 + (cb >> 2)) * K + (cb & 3) * 8;
    const ushort* gB0 = Bb + (size_t)(col0 + (ca >> 2)) * K + (ca & 3) * 8;
    const ushort* gB1 = Bb + (size_t)(col0 + (cb >> 2)) * K + (cb & 3) * 8;

    const int nkt = K >> 5;

    // Prologue: stage tile 0 into buffer 0.
    async16(gA0, sA + ca * 8);
    async16(gA1, sA + cb * 8);
    async16(gB0, sB + ca * 8);
    async16(gB1, sB + cb * 8);
    __syncthreads();   // vmcnt(0) drained: tile 0 visible

#pragma unroll 2
    for (int kt = 0; kt < nkt; ++kt) {
        const int cur = (kt & 1) * 4096;
        const int nxt = 4096 - cur;
        // Prefetch tile kt+1 into the other buffer; flies during compute.
        if (kt + 1 < nkt) {
            const size_t off = (size_t)(kt + 1) * 32;
            async16(gA0 + off, sA + nxt + ca * 8);
            async16(gA1 + off, sA + nxt + cb * 8);
            async16(gB0 + off, sB + nxt + ca * 8);
            async16(gB1 + off, sB + nxt + cb * 8);
        }

        bf16x8 af[4], bfr[4];
#pragma unroll
        for (int mi = 0; mi < 4; ++mi)
            af[mi] = *(const bf16x8*)&sA[cur + (wy * 64 + mi * 16 + lr) * 32 + lk * 8];
#pragma unroll
        for (int ni = 0; ni < 4; ++ni)
            bfr[ni] = *(const bf16x8*)&sB[cur + (wx * 64 + ni * 16 + lr) * 32 + lk * 8];

        __builtin_amdgcn_s_setprio(1);
#pragma unroll
        for (int mi = 0; mi < 4; ++mi)
#pragma unroll
            for (int ni = 0; ni < 4; ++ni)
                acc[mi][ni] = __builtin_amdgcn_mfma_f32_16x16x32_bf16(
                    af[mi], bfr[ni], acc[mi][ni], 0, 0, 0);
        __builtin_amdgcn_s_setprio(0);

        __syncthreads();   // drains vmcnt(0): next tile landed; lgkm done
    }

    // Epilogue. C/D layout (m89/m91-verified): col=lane&15, row=(lane>>4)*4+reg.
#pragma unroll
    for (int mi = 0; mi < 4; ++mi) {
#pragma unroll
        for (int ni = 0; ni < 4; ++ni) {
            const int col = col0 + wx * 64 + ni * 16 + lr;
            const float bv = biasb[col];
#pragma unroll
            for (int r = 0; r < 4; ++r) {
                const int row = row0 + wy * 64 + mi * 16 + lk * 4 + r;
                float v = acc[mi][ni][r] + bv;
                if (GELU)
                    v = 0.5f * v * (1.0f + erff(v * 0.70710678118654752f));
                const size_t idx = (size_t)e * M * N + (size_t)row * N + col;
                if (OUTF32) ((float*)Cv)[idx] = v;
                else        ((ushort*)Cv)[idx] = f2bf(v);
            }
        }
    }
}

extern "C" void kernel_launch(void* const* d_in, const int* in_sizes, int n_in,
                              void* d_out, int out_size, void* d_ws, size_t ws_size,
                              hipStream_t stream)
{
    const float* x  = (const float*)d_in[0];  // (8,4096,1024) flat expert-major
    const float* w1 = (const float*)d_in[1];  // (8,1024,2048)
    const float* b1 = (const float*)d_in[2];  // (8,2048)
    const float* w2 = (const float*)d_in[3];  // (8,2048,1024)
    const float* b2 = (const float*)d_in[4];  // (8,1024)
    float* out = (float*)d_out;               // (8,4096,1024) fp32

    const size_t W1T = 8ull * 2048 * 1024 * 2;   // 33.5 MB bf16, all experts
    const size_t W2T = 8ull * 1024 * 2048 * 2;   // 33.5 MB
    const size_t W1TE = 2048ull * 1024 * 2;      // 4.2 MB single expert
    const size_t W2TE = 1024ull * 2048 * 2;      // 4.2 MB
    const size_t XB_E = 4096ull * 1024 * 2;      // 8.4 MB bf16 x, one expert
    const size_t H_E  = 4096ull * 2048 * 2;      // 16.8 MB bf16 H, one expert

    char* ws = (char*)d_ws;

    // Level A: all-expert weight transposes + chunk of experts at once.
    int chunk = 0;
    for (int c = 8; c >= 1; c >>= 1)
        if (ws_size >= W1T + W2T + (size_t)c * (XB_E + H_E)) { chunk = c; break; }

    if (chunk >= 1) {
        ushort* w1t = (ushort*)ws;
        ushort* w2t = (ushort*)(ws + W1T);
        ushort* xb  = (ushort*)(ws + W1T + W2T);
        ushort* Hb  = (ushort*)(ws + W1T + W2T + (size_t)chunk * XB_E);

        transpose_cvt<<<dim3(2048 / 64, 1024 / 64, 8), 256, 0, stream>>>(
            w1, w1t, 1024, 2048);
        transpose_cvt<<<dim3(1024 / 64, 2048 / 64, 8), 256, 0, stream>>>(
            w2, w2t, 2048, 1024);

        for (int e0 = 0; e0 < 8; e0 += chunk) {
            const long n4 = (long)chunk * 4096 * 1024 / 4;
            cvt_f32_bf16<<<dim3(8192), 256, 0, stream>>>(
                (const float4*)(x + (size_t)e0 * 4096 * 1024), (uint2*)xb, n4);
            gemm_bt<1, 0><<<dim3(2048 / 128, 4096 / 128, chunk), 256, 0, stream>>>(
                xb, w1t + (size_t)e0 * 2048 * 1024, b1 + (size_t)e0 * 2048,
                Hb, 4096, 2048, 1024);
            gemm_bt<0, 1><<<dim3(1024 / 128, 4096 / 128, chunk), 256, 0, stream>>>(
                Hb, w2t + (size_t)e0 * 1024 * 2048, b2 + (size_t)e0 * 1024,
                out + (size_t)e0 * 4096 * 1024, 4096, 1024, 2048);
        }
        return;
    }

    // Level B/C: per-expert weights + token strips sized to ws.
    int strip = 0;
    if      (ws_size >= W1TE + W2TE + XB_E + H_E)             strip = 4096;
    else if (ws_size >= W1TE + W2TE + (XB_E + H_E) / 4)       strip = 1024;
    else                                                      strip = 128;

    ushort* w1t = (ushort*)ws;
    ushort* w2t = (ushort*)(ws + W1TE);
    ushort* xb  = (ushort*)(ws + W1TE + W2TE);
    ushort* Hb  = (ushort*)(ws + W1TE + W2TE + (size_t)strip * 1024 * 2);

    for (int e = 0; e < 8; ++e) {
        transpose_cvt<<<dim3(2048 / 64, 1024 / 64, 1), 256, 0, stream>>>(
            w1 + (size_t)e * 1024 * 2048, w1t, 1024, 2048);
        transpose_cvt<<<dim3(1024 / 64, 2048 / 64, 1), 256, 0, stream>>>(
            w2 + (size_t)e * 2048 * 1024, w2t, 2048, 1024);
        for (int s0 = 0; s0 < 4096; s0 += strip) {
            const long n4 = (long)strip * 1024 / 4;
            cvt_f32_bf16<<<dim3(2048), 256, 0, stream>>>(
                (const float4*)(x + ((size_t)e * 4096 + s0) * 1024), (uint2*)xb, n4);
            gemm_bt<1, 0><<<dim3(2048 / 128, strip / 128, 1), 256, 0, stream>>>(
                xb, w1t, b1 + (size_t)e * 2048, Hb, strip, 2048, 1024);
            gemm_bt<0, 1><<<dim3(1024 / 128, strip / 128, 1), 256, 0, stream>>>(
                Hb, w2t, b2 + (size_t)e * 1024,
                out + ((size_t)e * 4096 + s0) * 1024, strip, 1024, 2048);
        }
    }
}

// Round 3
// 690.851 us; speedup vs baseline: 1.1072x; 1.0854x over previous
//
#include <hip/hip_runtime.h>
#include <hip/hip_bf16.h>

// Experts MLP: B=4,E=8,S=1024,D=1024,H=2048. fp32 in/out, bf16 MFMA compute.
// Round 4: 256x256 8-phase GEMM (m201-family structure) in plain HIP:
//   512 thr / 8 waves (2Mx4N), BK=64, LDS = 4-slot ring of 16KB half-tiles
//   per matrix (128KB total), counted vmcnt(4) once per K-chunk (never 0 in
//   steady state), raw s_barrier (no drain), T2 XOR swizzle (s_phys =
//   s_log ^ (row&7)) applied on pre-swizzled global_load_lds SOURCE and on
//   ds_read addresses, T5 setprio around each 16-MFMA cluster.
//
// Schedule proof sketch (chunk g, phases p1-p4):
//   reads: a0(m0-3)@p1, b0(n0-1)@p1, b1(n2-3)@p2, a1(m4-7)@p3
//     => B-slots of chunk g dead after p2-end barrier, A-slots after p3-end.
//   stages: p1:(g+1).B1  -> slot of (g-1).B1, dead since (g-1,p2)   [safe]
//           p2:(g+1).A1  -> slot of (g-1).A1, dead since (g-1,p3)   [safe]
//           p3:(g+2).B0  -> slot of (g).B0,   dead since (g,p2)     [safe]
//           p4:(g+2).A0  -> slot of (g).A0,   dead since (g,p3)     [safe]
//   wait: vmcnt(4) at p4-end => everything <= (g+1).A1 landed = chunk g+1
//   complete before group g+1 reads it; outstanding = (g+2).{B0,A0} = 4 loads.
//   All barriers are hit uniformly by all 8 waves (uniform branches).

typedef __attribute__((ext_vector_type(8))) short bf16x8;
typedef __attribute__((ext_vector_type(4))) float f32x4;

__device__ __forceinline__ ushort f2bf(float f) {
    __hip_bfloat16 h = __float2bfloat16(f);
    return *(ushort*)&h;
}

__device__ __forceinline__ void async16(const ushort* g, ushort* l) {
    __builtin_amdgcn_global_load_lds(
        (const __attribute__((address_space(1))) unsigned int*)g,
        (__attribute__((address_space(3))) unsigned int*)l, 16, 0, 0);
}

__device__ __forceinline__ void bar_pinned() {
    __builtin_amdgcn_sched_barrier(0);
    __builtin_amdgcn_s_barrier();
    __builtin_amdgcn_sched_barrier(0);
}

// ---------------------------------------------------------------------------
// fp32 -> bf16 elementwise cast, float4 -> 4x bf16 per thread-iter.
// ---------------------------------------------------------------------------
__global__ __launch_bounds__(256) void cvt_f32_bf16(
    const float4* __restrict__ src, uint2* __restrict__ dst, long n4)
{
    long i = (long)blockIdx.x * 256 + threadIdx.x;
    const long stride = (long)gridDim.x * 256;
    for (; i < n4; i += stride) {
        float4 v = src[i];
        uint2 o;
        o.x = (unsigned)f2bf(v.x) | ((unsigned)f2bf(v.y) << 16);
        o.y = (unsigned)f2bf(v.z) | ((unsigned)f2bf(v.w) << 16);
        dst[i] = o;
    }
}

// ---------------------------------------------------------------------------
// Transpose+convert: fp32 (R,C) -> bf16 (C,R), per expert (grid.z).
// ---------------------------------------------------------------------------
__global__ __launch_bounds__(256) void transpose_cvt(
    const float* __restrict__ src, ushort* __restrict__ dst, int R, int C)
{
    __shared__ float tile[64][65];
    const int e = blockIdx.z;
    const float* s = src + (size_t)e * R * C;
    ushort* d = dst + (size_t)e * R * C;
    const int r0 = blockIdx.y * 64, c0 = blockIdx.x * 64;
    const int tid = threadIdx.x;

    const int tr = tid >> 4;          // 0..15
    const int tc = (tid & 15) * 4;    // 0..60
#pragma unroll
    for (int j = 0; j < 4; ++j) {
        const int row = tr + j * 16;
        float4 v = *(const float4*)&s[(size_t)(r0 + row) * C + c0 + tc];
        tile[row][tc] = v.x; tile[row][tc + 1] = v.y;
        tile[row][tc + 2] = v.z; tile[row][tc + 3] = v.w;
    }
    __syncthreads();

    const int cc = tid >> 2;          // dst row (src col) 0..63
    const int rq = (tid & 3) * 16;    // dst col base
    ushort o[16];
#pragma unroll
    for (int j = 0; j < 16; ++j) o[j] = f2bf(tile[rq + j][cc]);
    *(uint4*)&d[(size_t)(c0 + cc) * R + r0 + rq]     = *(uint4*)&o[0];
    *(uint4*)&d[(size_t)(c0 + cc) * R + r0 + rq + 8] = *(uint4*)&o[8];
}

// ---------------------------------------------------------------------------
// GEMM: C(M,N) = A(M,K) @ BT(N,K)^T + bias(fp32), optional exact GELU.
// 256x256 tile, 8 waves (2Mx4N), BK=64, 8-phase counted-vmcnt pipeline.
// grid(N/256, M/256, nE), 512 threads. M,N % 256 == 0; K % 64 == 0; K/64 >= 2.
// ---------------------------------------------------------------------------
template <int GELU, int OUTF32>
__global__ __launch_bounds__(512, 2) void gemm_bt(
    const ushort* __restrict__ A,
    const ushort* __restrict__ BT,
    const float* __restrict__ bias,
    void* __restrict__ Cv,
    int M, int N, int K)
{
    const int e = blockIdx.z;
    const ushort* Ab = A + (size_t)e * M * K;
    const ushort* Bb = BT + (size_t)e * N * K;
    const float* biasb = bias + (size_t)e * N;

    // T1: XCD-aware swizzle of the per-expert 2D grid (bijective when %8==0).
    const int gx = gridDim.x;
    const int nwg = gx * gridDim.y;
    int id = blockIdx.y * gx + blockIdx.x;
    if (nwg >= 8 && (nwg & 7) == 0)
        id = (id & 7) * (nwg >> 3) + (id >> 3);
    const int col0 = (id % gx) * 256;
    const int row0 = (id / gx) * 256;

    const int tid = threadIdx.x;
    const int lane = tid & 63;
    const int wave = tid >> 6;       // 0..7
    const int wy = wave >> 2;        // 0..1 : M-half owner
    const int wx = wave & 3;         // 0..3 : N-quarter owner
    const int lr = lane & 15;
    const int lk = lane >> 4;

    // 4 half-slots per matrix, 16KB each (128 rows x 64 bf16). 128KB total.
    __shared__ ushort sA[4 * 8192];
    __shared__ ushort sB[4 * 8192];

    f32x4 acc[8][4] = {};

    // ---- staging addresses (T2: pre-swizzled global source, linear LDS dest)
    const int trow = tid >> 3;                        // 0..63
    const int tcs  = ((tid & 7) ^ (trow & 7)) * 8;    // swizzled col, elems
    const ushort* gA = Ab + (size_t)(row0 + trow) * K + tcs;
    const ushort* gB = Bb + (size_t)(col0 + trow) * K + tcs;
    const int dst = tid * 8;                          // lane-linear LDS (ushort)

    const int nc = K >> 6;                            // 64-wide K-chunks

    // ---- frag-read swizzled column offsets (ushort units)
    const int sx0 = ((0 + lk) ^ (lr & 7)) * 8;        // ks = 0
    const int sx1 = ((4 + lk) ^ (lr & 7)) * 8;        // ks = 1
    const int bn  = (wx & 1) * 64;                    // row base inside B-half

    auto stageA = [&](int c, int h) {
        const int slot = ((2 * c + h) & 3) * 8192;
        const ushort* g = gA + ((size_t)h * 128) * K + c * 64;
        async16(g,                  (ushort*)&sA[slot + dst]);
        async16(g + (size_t)64 * K, (ushort*)&sA[slot + 4096 + dst]);
    };
    auto stageB = [&](int c, int h) {
        const int slot = ((2 * c + h) & 3) * 8192;
        const ushort* g = gB + ((size_t)h * 128) * K + c * 64;
        async16(g,                  (ushort*)&sB[slot + dst]);
        async16(g + (size_t)64 * K, (ushort*)&sB[slot + 4096 + dst]);
    };

    // ---- prologue: chunk0 {B0,A0,B1,A1} + chunk1 {B0,A0} = 12 loads/thread
    stageB(0, 0); stageA(0, 0); stageB(0, 1); stageA(0, 1);
    if (nc > 1) {
        stageB(1, 0); stageA(1, 0);
        asm volatile("s_waitcnt vmcnt(4)" ::: "memory");  // chunk0 landed
    } else {
        asm volatile("s_waitcnt vmcnt(0)" ::: "memory");
    }
    bar_pinned();

#pragma unroll 2
    for (int g = 0; g < nc; ++g) {
        const int sa = ((2 * g + wy) & 3) * 8192;         // my A half-slot
        const int sb = ((2 * g + (wx >> 1)) & 3) * 8192;  // my B half-slot

        bf16x8 a0[4][2], a1[4][2], b0[2][2], b1[2][2];

        // ===== phase 1: read a0(m0-3) + b0(n0-1); stage (g+1).B1; Q(m0-3,n0-1)
#pragma unroll
        for (int m = 0; m < 4; ++m) {
            a0[m][0] = *(const bf16x8*)&sA[sa + (m * 16 + lr) * 64 + sx0];
            a0[m][1] = *(const bf16x8*)&sA[sa + (m * 16 + lr) * 64 + sx1];
        }
#pragma unroll
        for (int n = 0; n < 2; ++n) {
            b0[n][0] = *(const bf16x8*)&sB[sb + (bn + n * 16 + lr) * 64 + sx0];
            b0[n][1] = *(const bf16x8*)&sB[sb + (bn + n * 16 + lr) * 64 + sx1];
        }
        if (g + 1 < nc) stageB(g + 1, 1);
        bar_pinned();
        __builtin_amdgcn_s_setprio(1);
#pragma unroll
        for (int m = 0; m < 4; ++m)
#pragma unroll
            for (int n = 0; n < 2; ++n) {
                acc[m][n] = __builtin_amdgcn_mfma_f32_16x16x32_bf16(
                    a0[m][0], b0[n][0], acc[m][n], 0, 0, 0);
                acc[m][n] = __builtin_amdgcn_mfma_f32_16x16x32_bf16(
                    a0[m][1], b0[n][1], acc[m][n], 0, 0, 0);
            }
        __builtin_amdgcn_s_setprio(0);
        bar_pinned();

        // ===== phase 2: read b1(n2-3); stage (g+1).A1; Q(m0-3,n2-3)
#pragma unroll
        for (int n = 0; n < 2; ++n) {
            b1[n][0] = *(const bf16x8*)&sB[sb + (bn + (n + 2) * 16 + lr) * 64 + sx0];
            b1[n][1] = *(const bf16x8*)&sB[sb + (bn + (n + 2) * 16 + lr) * 64 + sx1];
        }
        if (g + 1 < nc) stageA(g + 1, 1);
        bar_pinned();
        __builtin_amdgcn_s_setprio(1);
#pragma unroll
        for (int m = 0; m < 4; ++m)
#pragma unroll
            for (int n = 0; n < 2; ++n) {
                acc[m][n + 2] = __builtin_amdgcn_mfma_f32_16x16x32_bf16(
                    a0[m][0], b1[n][0], acc[m][n + 2], 0, 0, 0);
                acc[m][n + 2] = __builtin_amdgcn_mfma_f32_16x16x32_bf16(
                    a0[m][1], b1[n][1], acc[m][n + 2], 0, 0, 0);
            }
        __builtin_amdgcn_s_setprio(0);
        bar_pinned();

        // ===== phase 3: read a1(m4-7); stage (g+2).B0; Q(m4-7,n0-1)
#pragma unroll
        for (int m = 0; m < 4; ++m) {
            a1[m][0] = *(const bf16x8*)&sA[sa + ((m + 4) * 16 + lr) * 64 + sx0];
            a1[m][1] = *(const bf16x8*)&sA[sa + ((m + 4) * 16 + lr) * 64 + sx1];
        }
        if (g + 2 < nc) stageB(g + 2, 0);
        bar_pinned();
        __builtin_amdgcn_s_setprio(1);
#pragma unroll
        for (int m = 0; m < 4; ++m)
#pragma unroll
            for (int n = 0; n < 2; ++n) {
                acc[m + 4][n] = __builtin_amdgcn_mfma_f32_16x16x32_bf16(
                    a1[m][0], b0[n][0], acc[m + 4][n], 0, 0, 0);
                acc[m + 4][n] = __builtin_amdgcn_mfma_f32_16x16x32_bf16(
                    a1[m][1], b0[n][1], acc[m + 4][n], 0, 0, 0);
            }
        __builtin_amdgcn_s_setprio(0);
        bar_pinned();

        // ===== phase 4: stage (g+2).A0; Q(m4-7,n2-3); counted vmcnt; end bar
        if (g + 2 < nc) stageA(g + 2, 0);
        bar_pinned();
        __builtin_amdgcn_s_setprio(1);
#pragma unroll
        for (int m = 0; m < 4; ++m)
#pragma unroll
            for (int n = 0; n < 2; ++n) {
                acc[m + 4][n + 2] = __builtin_amdgcn_mfma_f32_16x16x32_bf16(
                    a1[m][0], b1[n][0], acc[m + 4][n + 2], 0, 0, 0);
                acc[m + 4][n + 2] = __builtin_amdgcn_mfma_f32_16x16x32_bf16(
                    a1[m][1], b1[n][1], acc[m + 4][n + 2], 0, 0, 0);
            }
        __builtin_amdgcn_s_setprio(0);
        if (g + 2 < nc) {
            asm volatile("s_waitcnt vmcnt(4)" ::: "memory");  // chunk g+1 ready
        } else {
            asm volatile("s_waitcnt vmcnt(0)" ::: "memory");  // tail drain
        }
        bar_pinned();
    }

    // ---- epilogue. C/D layout (m89/m91): col=lane&15, row=(lane>>4)*4+reg.
#pragma unroll
    for (int mi = 0; mi < 8; ++mi) {
#pragma unroll
        for (int ni = 0; ni < 4; ++ni) {
            const int col = col0 + wx * 64 + ni * 16 + lr;
            const float bv = biasb[col];
#pragma unroll
            for (int r = 0; r < 4; ++r) {
                const int row = row0 + wy * 128 + mi * 16 + lk * 4 + r;
                float v = acc[mi][ni][r] + bv;
                if (GELU)
                    v = 0.5f * v * (1.0f + erff(v * 0.70710678118654752f));
                const size_t idx = (size_t)e * M * N + (size_t)row * N + col;
                if (OUTF32) ((float*)Cv)[idx] = v;
                else        ((ushort*)Cv)[idx] = f2bf(v);
            }
        }
    }
}

extern "C" void kernel_launch(void* const* d_in, const int* in_sizes, int n_in,
                              void* d_out, int out_size, void* d_ws, size_t ws_size,
                              hipStream_t stream)
{
    const float* x  = (const float*)d_in[0];  // (8,4096,1024) flat expert-major
    const float* w1 = (const float*)d_in[1];  // (8,1024,2048)
    const float* b1 = (const float*)d_in[2];  // (8,2048)
    const float* w2 = (const float*)d_in[3];  // (8,2048,1024)
    const float* b2 = (const float*)d_in[4];  // (8,1024)
    float* out = (float*)d_out;               // (8,4096,1024) fp32

    const size_t W1T = 8ull * 2048 * 1024 * 2;   // 33.5 MB bf16, all experts
    const size_t W2T = 8ull * 1024 * 2048 * 2;   // 33.5 MB
    const size_t W1TE = 2048ull * 1024 * 2;      // 4.2 MB single expert
    const size_t W2TE = 1024ull * 2048 * 2;      // 4.2 MB
    const size_t XB_E = 4096ull * 1024 * 2;      // 8.4 MB bf16 x, one expert
    const size_t H_E  = 4096ull * 2048 * 2;      // 16.8 MB bf16 H, one expert

    char* ws = (char*)d_ws;

    // Level A: all-expert weight transposes + chunk of experts at once.
    int chunk = 0;
    for (int c = 8; c >= 1; c >>= 1)
        if (ws_size >= W1T + W2T + (size_t)c * (XB_E + H_E)) { chunk = c; break; }

    if (chunk >= 1) {
        ushort* w1t = (ushort*)ws;
        ushort* w2t = (ushort*)(ws + W1T);
        ushort* xb  = (ushort*)(ws + W1T + W2T);
        ushort* Hb  = (ushort*)(ws + W1T + W2T + (size_t)chunk * XB_E);

        transpose_cvt<<<dim3(2048 / 64, 1024 / 64, 8), 256, 0, stream>>>(
            w1, w1t, 1024, 2048);
        transpose_cvt<<<dim3(1024 / 64, 2048 / 64, 8), 256, 0, stream>>>(
            w2, w2t, 2048, 1024);

        for (int e0 = 0; e0 < 8; e0 += chunk) {
            const long n4 = (long)chunk * 4096 * 1024 / 4;
            cvt_f32_bf16<<<dim3(8192), 256, 0, stream>>>(
                (const float4*)(x + (size_t)e0 * 4096 * 1024), (uint2*)xb, n4);
            gemm_bt<1, 0><<<dim3(2048 / 256, 4096 / 256, chunk), 512, 0, stream>>>(
                xb, w1t + (size_t)e0 * 2048 * 1024, b1 + (size_t)e0 * 2048,
                Hb, 4096, 2048, 1024);
            gemm_bt<0, 1><<<dim3(1024 / 256, 4096 / 256, chunk), 512, 0, stream>>>(
                Hb, w2t + (size_t)e0 * 1024 * 2048, b2 + (size_t)e0 * 1024,
                out + (size_t)e0 * 4096 * 1024, 4096, 1024, 2048);
        }
        return;
    }

    // Level B/C: per-expert weights + token strips sized to ws (strip % 256).
    int strip = 0;
    if      (ws_size >= W1TE + W2TE + XB_E + H_E)             strip = 4096;
    else if (ws_size >= W1TE + W2TE + (XB_E + H_E) / 4)       strip = 1024;
    else                                                      strip = 256;

    ushort* w1t = (ushort*)ws;
    ushort* w2t = (ushort*)(ws + W1TE);
    ushort* xb  = (ushort*)(ws + W1TE + W2TE);
    ushort* Hb  = (ushort*)(ws + W1TE + W2TE + (size_t)strip * 1024 * 2);

    for (int e = 0; e < 8; ++e) {
        transpose_cvt<<<dim3(2048 / 64, 1024 / 64, 1), 256, 0, stream>>>(
            w1 + (size_t)e * 1024 * 2048, w1t, 1024, 2048);
        transpose_cvt<<<dim3(1024 / 64, 2048 / 64, 1), 256, 0, stream>>>(
            w2 + (size_t)e * 2048 * 1024, w2t, 2048, 1024);
        for (int s0 = 0; s0 < 4096; s0 += strip) {
            const long n4 = (long)strip * 1024 / 4;
            cvt_f32_bf16<<<dim3(2048), 256, 0, stream>>>(
                (const float4*)(x + ((size_t)e * 4096 + s0) * 1024), (uint2*)xb, n4);
            gemm_bt<1, 0><<<dim3(2048 / 256, strip / 256, 1), 512, 0, stream>>>(
                xb, w1t, b1 + (size_t)e * 2048, Hb, strip, 2048, 1024);
            gemm_bt<0, 1><<<dim3(1024 / 256, strip / 256, 1), 512, 0, stream>>>(
                Hb, w2t, b2 + (size_t)e * 1024,
                out + ((size_t)e * 4096 + s0) * 1024, strip, 1024, 2048);
        }
    }
}